// Round 15
// baseline (127.380 us; speedup 1.0000x reference)
//
#include <hip/hip_runtime.h>
#include <hip/hip_bf16.h>

// Shapes
#define B_SZ   256
#define C_SZ   1024
#define HW     49
#define KDIM   50176        // C*H*W
#define DHID   768
#define NCLS   5

typedef __bf16 bf16x8 __attribute__((ext_vector_type(8)));
typedef __bf16 bf16x4 __attribute__((ext_vector_type(4)));
typedef float  f32x4  __attribute__((ext_vector_type(4)));

#define GLOAD_LDS16(gsrc, ldst) \
  __builtin_amdgcn_global_load_lds((__attribute__((address_space(1))) void*)(gsrc), \
                                   (__attribute__((address_space(3))) void*)(ldst), 16, 0, 0)

#define FENCE()   asm volatile("" ::: "memory")
#define BARRIER() do { \
    asm volatile("s_waitcnt lgkmcnt(0)" ::: "memory"); \
    __builtin_amdgcn_s_barrier(); \
    asm volatile("" ::: "memory"); \
  } while (0)

// ---------------------------------------------------------------------------
// Kernel A: per-(b,c) spatial max, pcam = feat*max -> bf16 (ws), copy feat -> out
// ---------------------------------------------------------------------------
__global__ __launch_bounds__(256) void pcam_kernel(const float* __restrict__ feat,
                                                   float* __restrict__ feat_out,
                                                   __bf16* __restrict__ pcam) {
  __shared__ float sv[1568];
  __shared__ float smax[32];
  const int tid = threadIdx.x;
  const size_t base = (size_t)blockIdx.x * 1568;

  const float4* src4 = (const float4*)(feat + base);
  float4* dst4 = (float4*)(feat_out + base);
  #pragma unroll
  for (int i = 0; i < 2; ++i) {
    int idx = tid + i * 256;
    if (idx < 392) {
      float4 v = src4[idx];
      dst4[idx] = v;
      ((float4*)sv)[idx] = v;
    }
  }
  __syncthreads();

  {
    const int r = tid >> 3, p = tid & 7;
    float mx = -INFINITY;
    for (int i = p; i < HW; i += 8) mx = fmaxf(mx, sv[r * HW + i]);
    #pragma unroll
    for (int off = 1; off < 8; off <<= 1) mx = fmaxf(mx, __shfl_xor(mx, off));
    if (p == 0) smax[r] = mx;
  }
  __syncthreads();

  for (int i = tid; i < 1568; i += 256) {
    int r = (i * 1338) >> 16;        // i/49 exact for i<1568
    float v = sv[i] * smax[r];
    pcam[base + i] = (__bf16)v;
  }
}

// ---------------------------------------------------------------------------
// Kernel R: repack W1 fp32 row-major -> bf16 MFMA-fragment-packed:
//   Wp[f][kc][l][e] = bf16(W1[f*16 + (l&15)][kc*32 + (l>>4)*8 + e])
// so a GEMM wave's B-fragment load is ONE contiguous 1KB instruction.
// Block = (f 0..47, strip ss 0..31 of 49 kc = 1568 k). Transpose via LDS:
// reads coalesced (16 rows x 896B per sub-strip), writes contiguous
// (tid-consecutive 16B granules = 1KB/wave). 231 MB streaming ~ 34us.
// ---------------------------------------------------------------------------
__global__ __launch_bounds__(256) void repack_kernel(const float* __restrict__ W1,
                                                     __bf16* __restrict__ Wp) {
  __shared__ float ls[16 * 228];   // pitch 228 breaks bank alignment
  const int tid = threadIdx.x;
  const int f   = blockIdx.x >> 5;     // 0..47
  const int ss  = blockIdx.x & 31;     // 0..31

  for (int sub = 0; sub < 7; ++sub) {
    const size_t k0 = (size_t)ss * 1568 + sub * 224;
    #pragma unroll
    for (int it = 0; it < 4; ++it) {
      const int fi = it * 256 + tid;       // < 896 = 16 rows x 56 float4
      if (fi < 896) {
        const int row  = fi / 56;
        const int col4 = fi % 56;
        const float4 v = *(const float4*)(W1 + (size_t)(f * 16 + row) * KDIM + k0 + col4 * 4);
        *(float4*)(ls + row * 228 + col4 * 4) = v;
      }
    }
    __syncthreads();
    #pragma unroll
    for (int it = 0; it < 2; ++it) {
      const int oi = it * 256 + tid;       // < 448 = 7 kc x 4 oct x 16 rr
      if (oi < 448) {
        const int rr  = oi & 15;
        const int oct = (oi >> 4) & 3;
        const int kcl = oi >> 6;
        const float* src = ls + rr * 228 + kcl * 32 + oct * 8;
        bf16x8 o;
        #pragma unroll
        for (int e = 0; e < 8; ++e) o[e] = (__bf16)src[e];
        const size_t kc = (size_t)ss * 49 + sub * 7 + kcl;
        *(bf16x8*)(Wp + (((size_t)f * 1568 + kc) * 64 + oct * 16 + rr) * 8) = o;
      }
    }
    __syncthreads();
  }
}

// ---------------------------------------------------------------------------
// Kernel B (v13 = PACKED-B STREAMING GEMM): B-fragments load straight from
// packed Wp to a 3-set static register ring (contiguous 1KB instrs, no LDS,
// no barrier on the B path); A (pcam row-major) via global_load_lds double
// buffer (R13 path). One vmcnt(4)+barrier per K-step: in-order counter ->
// completes B(t+1)+A(t+1), keeps B(t+2) in flight across the whole phase.
// BM=256 (W1 once), BN=256 (pcam x3), BK=64, 8 waves, KSPLIT=85 -> 255 blk.
// 12-step padded loop (4 x 3-phase, static set rotation). bf16 partials.
// ---------------------------------------------------------------------------
#define BM 256
#define BN 256
#define BK 64
#define NT 3
#define KSPLIT 85
#define KSTEPS 784          // KDIM/BK

__global__ __launch_bounds__(512, 1) void gemm1_kernel(const __bf16* __restrict__ pcam,
                                                       const __bf16* __restrict__ Wp,
                                                       __bf16* __restrict__ h_part) {
  __shared__ __bf16 Asm[2][BM * BK];   // 2 x 32 KB (A only)

  const int tid  = threadIdx.x;
  const int lane = tid & 63;
  const int w    = tid >> 6;        // 0..7 : wave owns n-rows nt*256+w*32..+31
  const int c_   = lane & 15;
  const int q_   = lane >> 4;
  const int nt   = blockIdx.x;      // 0..2
  const int ks   = blockIdx.y;      // 0..84
  const int s0   = (ks * KSTEPS) / KSPLIT;
  const int s1   = ((ks + 1) * KSTEPS) / KSPLIT;   // 9-10 steps

  // A staging (R13 verbatim): source 16B-unit pre-swizzled ^(m&7), linear dest
  unsigned a_off[4];
  #pragma unroll
  for (int it = 0; it < 4; ++it) {
    const unsigned ug = it * 512 + tid;
    const unsigned m  = ug >> 3;
    a_off[it] = m * (unsigned)KDIM + (((ug & 7) ^ (m & 7)) * 8u);
  }

  // B fragment stream bases: frag f' = nt*16 + w*2 + {0,1}; addr(kc) = base + kc*512 elems
  const __bf16* pb0 = Wp + (size_t)(nt * 16 + w * 2 + 0) * 1568 * 512 + lane * 8;
  const __bf16* pb1 = Wp + (size_t)(nt * 16 + w * 2 + 1) * 1568 * 512 + lane * 8;

  f32x4 acc[16][2];
  #pragma unroll
  for (int i = 0; i < 16; ++i)
    #pragma unroll
    for (int j = 0; j < 2; ++j) acc[i][j] = f32x4{0.f, 0.f, 0.f, 0.f};

  // 3 B reg sets x {kc0/kc1 x frag0/frag1}, static names (rule #20)
  bf16x8 b0_0a, b0_0b, b0_1a, b0_1b;
  bf16x8 b1_0a, b1_0b, b1_1a, b1_1b;
  bf16x8 b2_0a, b2_0b, b2_1a, b2_1b;

#define ISSUE_B(K0a, K0b, K1a, K1b, t) do { \
    const size_t kb = (size_t)(t) * 2 * 512; \
    K0a = *(const bf16x8*)(pb0 + kb); \
    K0b = *(const bf16x8*)(pb1 + kb); \
    K1a = *(const bf16x8*)(pb0 + kb + 512); \
    K1b = *(const bf16x8*)(pb1 + kb + 512); \
    FENCE(); \
  } while (0)

#define ISSUE_A(par, t) do { \
    const unsigned ka = (unsigned)(t) * BK; \
    _Pragma("unroll") \
    for (int it = 0; it < 4; ++it) \
      GLOAD_LDS16(pcam + a_off[it] + ka, (char*)Asm[par] + it * 8192 + w * 1024); \
    FENCE(); \
  } while (0)

#define COMPUTE(par, K0a, K0b, K1a, K1b) do { \
    _Pragma("unroll") \
    for (int ksub = 0; ksub < 2; ++ksub) { \
      const bf16x8 f0 = ksub ? K1a : K0a; \
      const bf16x8 f1 = ksub ? K1b : K0b; \
      const int u = ksub * 4 + q_; \
      _Pragma("unroll") \
      for (int i = 0; i < 16; ++i) { \
        const int m = i * 16 + c_; \
        const bf16x8 af = *(const bf16x8*)((const char*)Asm[par] + m * 128 + ((u ^ (m & 7)) << 4)); \
        acc[i][0] = __builtin_amdgcn_mfma_f32_16x16x32_bf16(af, f0, acc[i][0], 0, 0, 0); \
        acc[i][1] = __builtin_amdgcn_mfma_f32_16x16x32_bf16(af, f1, acc[i][1], 0, 0, 0); \
      } \
    } \
  } while (0)

  // ---- prologue (s1-s0 >= 9 always)
  ISSUE_A(0, s0);
  ISSUE_B(b0_0a, b0_0b, b0_1a, b0_1b, s0);
  ISSUE_B(b1_0a, b1_0b, b1_1a, b1_1b, s0 + 1);
  asm volatile("s_waitcnt vmcnt(4)" ::: "memory");   // A(s0)+B(s0) done; B(s0+1) in flight
  BARRIER();
  ISSUE_A(1, s0 + 1);

  // steady: per step outstanding peaks at 12 (B(t+1),A(t+1),B(t+2));
  // vmcnt(4) completes the oldest 8 = B(t+1)+A(t+1).
#define STEP(JI, CS0a, CS0b, CS1a, CS1b, IS0a, IS0b, IS1a, IS1b) do { \
    const int r  = jo * 3 + (JI); \
    const int t  = s0 + r; \
    const int tc = (t + 2 < s1) ? (t + 2) : (s1 - 1); \
    ISSUE_B(IS0a, IS0b, IS1a, IS1b, tc); \
    if (t < s1) COMPUTE((r & 1), CS0a, CS0b, CS1a, CS1b); \
    asm volatile("s_waitcnt vmcnt(4)" ::: "memory"); \
    BARRIER(); \
    ISSUE_A((r & 1), tc); \
  } while (0)

  for (int jo = 0; jo < 4; ++jo) {   // 12 padded steps >= 10
    STEP(0, b0_0a, b0_0b, b0_1a, b0_1b, b2_0a, b2_0b, b2_1a, b2_1b);
    STEP(1, b1_0a, b1_0b, b1_1a, b1_1b, b0_0a, b0_0b, b0_1a, b0_1b);
    STEP(2, b2_0a, b2_0b, b2_1a, b2_1b, b1_0a, b1_0b, b1_1a, b1_1b);
  }
#undef STEP

  // ---- epilogue: bf16 partial slice [ks][n][m] (m fastest, 4 per lane)
  __bf16* out = h_part + (size_t)ks * DHID * B_SZ;
  #pragma unroll
  for (int j = 0; j < 2; ++j) {
    const int n = nt * BN + w * 32 + j * 16 + c_;
    #pragma unroll
    for (int i = 0; i < 16; ++i) {
      const int mb = i * 16 + q_ * 4;
      bf16x4 pv;
      pv[0] = (__bf16)acc[i][j][0]; pv[1] = (__bf16)acc[i][j][1];
      pv[2] = (__bf16)acc[i][j][2]; pv[3] = (__bf16)acc[i][j][3];
      *(bf16x4*)(out + (size_t)n * B_SZ + mb) = pv;
    }
  }
#undef ISSUE_B
#undef ISSUE_A
#undef COMPUTE
}

// ---------------------------------------------------------------------------
// Kernel C: reduce bf16 split-K partials, add b1, relu -> h[m][n] (fp32)
// ---------------------------------------------------------------------------
__global__ __launch_bounds__(256) void reduce_kernel(const __bf16* __restrict__ h_part,
                                                     const float* __restrict__ b1,
                                                     float* __restrict__ h) {
  const int n = blockIdx.x;
  const int m = threadIdx.x;
  float s = 0.f;
  #pragma unroll 5
  for (int ks = 0; ks < KSPLIT; ++ks)
    s += (float)h_part[((size_t)ks * DHID + n) * B_SZ + m];
  float v = s + b1[n];
  h[(size_t)m * DHID + n] = v > 0.f ? v : 0.f;
}

// ---------------------------------------------------------------------------
// Kernel D: logits = h @ W2^T + b2. One wave per batch row.
// ---------------------------------------------------------------------------
__global__ __launch_bounds__(64) void head_kernel(const float* __restrict__ h,
                                                  const float* __restrict__ W2,
                                                  const float* __restrict__ b2,
                                                  float* __restrict__ logits) {
  const int m = blockIdx.x;
  const int lane = threadIdx.x;
  float hv[12];
  #pragma unroll
  for (int j = 0; j < 12; ++j) hv[j] = h[(size_t)m * DHID + j * 64 + lane];
  #pragma unroll
  for (int c = 0; c < NCLS; ++c) {
    float s = 0.f;
    #pragma unroll
    for (int j = 0; j < 12; ++j) s += hv[j] * W2[c * DHID + j * 64 + lane];
    #pragma unroll
    for (int off = 32; off > 0; off >>= 1) s += __shfl_xor(s, off);
    if (lane == 0) logits[m * NCLS + c] = s + b2[c];
  }
}

// ---------------------------------------------------------------------------
extern "C" void kernel_launch(void* const* d_in, const int* in_sizes, int n_in,
                              void* d_out, int out_size, void* d_ws, size_t ws_size,
                              hipStream_t stream) {
  const float* feat = (const float*)d_in[0];
  const float* W1   = (const float*)d_in[1];
  const float* b1   = (const float*)d_in[2];
  const float* W2   = (const float*)d_in[3];
  const float* b2   = (const float*)d_in[4];

  float* logits   = (float*)d_out;
  float* feat_out = (float*)d_out + (size_t)B_SZ * NCLS;

  char* ws = (char*)d_ws;
  __bf16* pcam   = (__bf16*)ws;                                  // 25,690,112 B
  __bf16* Wp     = (__bf16*)(ws + 25690112);                     // 77,070,336 B
  __bf16* h_part = (__bf16*)(ws + 25690112 + 77070336);          // 33,423,360 B
  float*  h      = (float*) (ws + 25690112 + 77070336 + 33423360); // 786,432 B

  pcam_kernel<<<(B_SZ * C_SZ) / 32, 256, 0, stream>>>(feat, feat_out, pcam);
  repack_kernel<<<48 * 32, 256, 0, stream>>>(W1, Wp);
  gemm1_kernel<<<dim3(NT, KSPLIT), 512, 0, stream>>>(pcam, Wp, h_part);
  reduce_kernel<<<DHID, 256, 0, stream>>>(h_part, b1, h);
  head_kernel<<<B_SZ, 64, 0, stream>>>(h, W2, b2, logits);
}

// Round 16
// 92.713 us; speedup vs baseline: 1.3739x; 1.3739x over previous
//
#include <hip/hip_runtime.h>
#include <hip/hip_bf16.h>

// Shapes
#define B_SZ   256
#define C_SZ   1024
#define HW     49
#define KDIM   50176        // C*H*W
#define DHID   768
#define NCLS   5

typedef __bf16 bf16x8 __attribute__((ext_vector_type(8)));
typedef __bf16 bf16x4 __attribute__((ext_vector_type(4)));
typedef float  f32x4  __attribute__((ext_vector_type(4)));

#define GLOAD_LDS16(gsrc, ldst) \
  __builtin_amdgcn_global_load_lds((__attribute__((address_space(1))) void*)(gsrc), \
                                   (__attribute__((address_space(3))) void*)(ldst), 16, 0, 0)

#define BARRIER() do { \
    asm volatile("s_waitcnt lgkmcnt(0)" ::: "memory"); \
    __builtin_amdgcn_s_barrier(); \
    asm volatile("" ::: "memory"); \
  } while (0)

// ---------------------------------------------------------------------------
// Kernel A: per-(b,c) spatial max, pcam = feat*max -> bf16 (ws), copy feat -> out
// ---------------------------------------------------------------------------
__global__ __launch_bounds__(256) void pcam_kernel(const float* __restrict__ feat,
                                                   float* __restrict__ feat_out,
                                                   __bf16* __restrict__ pcam) {
  __shared__ float sv[1568];
  __shared__ float smax[32];
  const int tid = threadIdx.x;
  const size_t base = (size_t)blockIdx.x * 1568;

  const float4* src4 = (const float4*)(feat + base);
  float4* dst4 = (float4*)(feat_out + base);
  #pragma unroll
  for (int i = 0; i < 2; ++i) {
    int idx = tid + i * 256;
    if (idx < 392) {
      float4 v = src4[idx];
      dst4[idx] = v;
      ((float4*)sv)[idx] = v;
    }
  }
  __syncthreads();

  {
    const int r = tid >> 3, p = tid & 7;
    float mx = -INFINITY;
    for (int i = p; i < HW; i += 8) mx = fmaxf(mx, sv[r * HW + i]);
    #pragma unroll
    for (int off = 1; off < 8; off <<= 1) mx = fmaxf(mx, __shfl_xor(mx, off));
    if (p == 0) smax[r] = mx;
  }
  __syncthreads();

  for (int i = tid; i < 1568; i += 256) {
    int r = (i * 1338) >> 16;        // i/49 exact for i<1568
    float v = sv[i] * smax[r];
    pcam[base + i] = (__bf16)v;
  }
}

// ---------------------------------------------------------------------------
// Kernel B (v14 = R13 + WAVE QUADRANTS): model from R1-R15: time =
// VMEM-instrs x ~90cyc/CU + LDS-read slop per step. R13's 1D wave layout
// made every wave re-read the WHOLE 32KB A-tile per step (34 ds_read_b128/
// wave/step, 272KB/CU/step = 1.33us slop). Fix: 2Mx4N wave grid, wave tile
// 128x32 (8 m-frags x 2 n-frags) -> 20 reads + 32 MFMA per wave per step
// (MFMA:read 1.6 vs 0.94), block LDS reads 272->160KB/step. Everything
// else byte-identical to R13 (coalesced reg-staged B, DMA A, double-buf,
// drain vmcnt(0) before WRITE_B, one barrier/step, bf16 partials).
// BM=256, BN=128, BK=64, NT=6, KSPLIT=42 -> 252 blocks, 1 blk/CU.
// ---------------------------------------------------------------------------
#define BM 256
#define BN 128
#define BK 64
#define NT 6
#define KSPLIT 42
#define KSTEPS 784          // KDIM/BK

__global__ __launch_bounds__(512, 1) void gemm1_kernel(const __bf16* __restrict__ pcam,
                                                       const float* __restrict__ W1,
                                                       __bf16* __restrict__ h_part) {
  __shared__ __bf16 Asm[2][BM * BK];   // 2 x 32 KB
  __shared__ __bf16 Bsm[2][BN * BK];   // 2 x 16 KB

  const int tid  = threadIdx.x;
  const int lane = tid & 63;
  const int w    = tid >> 6;        // 0..7
  const int wm   = w >> 2;          // 0..1 : 128-row slab
  const int wn   = w & 3;           // 0..3 : 32-col slab
  const int c_   = lane & 15;
  const int q_   = lane >> 4;       // 0..3
  const int n0   = blockIdx.x * BN;
  const int ks   = blockIdx.y;
  const int s0   = (ks * KSTEPS) / KSPLIT;
  const int s1   = ((ks + 1) * KSTEPS) / KSPLIT;

  // ---- A staging (global_load_lds, R13 verbatim): 2048 16B-units, 4/thread;
  // row m=ug>>3; source unit (ug&7)^(m&7); dest linear.
  unsigned a_off[4];
  #pragma unroll
  for (int it = 0; it < 4; ++it) {
    const unsigned ug = it * 512 + tid;
    const unsigned m  = ug >> 3;
    a_off[it] = m * (unsigned)KDIM + (((ug & 7) ^ (m & 7)) * 8u);
  }

  // ---- B staging (coalesced, R13 verbatim): instr i reads rows w*16+i*4+q_,
  // 16B at c_*16 within the row's 256B chunk -> 4 x 256B contiguous.
  const float* bsrc[4];
  #pragma unroll
  for (int i = 0; i < 4; ++i)
    bsrc[i] = W1 + (size_t)(n0 + w * 16 + i * 4 + q_) * KDIM + c_ * 4;

  int bwr[4];
  #pragma unroll
  for (int i = 0; i < 4; ++i) {
    const int r = w * 16 + i * 4 + q_;
    bwr[i] = r * 128 + (((c_ >> 1) ^ (r & 7)) << 4) + ((c_ & 1) << 3);
  }

  f32x4 acc[8][2];
  #pragma unroll
  for (int i = 0; i < 8; ++i)
    #pragma unroll
    for (int j = 0; j < 2; ++j) acc[i][j] = f32x4{0.f, 0.f, 0.f, 0.f};

  f32x4 bq0, bq1, bq2, bq3;          // B stage regs (one K-step)

#define ISSUE_A(bi, s) do { \
    const unsigned ka = (unsigned)(s) * BK; \
    _Pragma("unroll") \
    for (int it = 0; it < 4; ++it) \
      GLOAD_LDS16(pcam + a_off[it] + ka, (char*)Asm[bi] + it * 8192 + w * 1024); \
  } while (0)

#define ISSUE_B(s) do { \
    const size_t kb = (size_t)(s) * BK; \
    bq0 = *(const f32x4*)(bsrc[0] + kb); \
    bq1 = *(const f32x4*)(bsrc[1] + kb); \
    bq2 = *(const f32x4*)(bsrc[2] + kb); \
    bq3 = *(const f32x4*)(bsrc[3] + kb); \
  } while (0)

#define WRITE_B(bi) do { \
    _Pragma("unroll") \
    for (int i = 0; i < 4; ++i) { \
      const f32x4 v = (i == 0) ? bq0 : (i == 1) ? bq1 : (i == 2) ? bq2 : bq3; \
      bf16x4 bv; \
      bv[0] = (__bf16)v[0]; bv[1] = (__bf16)v[1]; \
      bv[2] = (__bf16)v[2]; bv[3] = (__bf16)v[3]; \
      *(bf16x4*)((char*)Bsm[bi] + bwr[i]) = bv; \
    } \
  } while (0)

// Wave-quadrant compute: wave (wm,wn) owns rows wm*128+i*16 (i<8),
// cols wn*32+j*16 (j<2). 20 ds_reads + 32 MFMA per step.
#define COMPUTE(bi) do { \
    _Pragma("unroll") \
    for (int ksub = 0; ksub < 2; ++ksub) { \
      const int u = ksub * 4 + q_; \
      bf16x8 bfr[2]; \
      _Pragma("unroll") \
      for (int j = 0; j < 2; ++j) { \
        const int rn = wn * 32 + j * 16 + c_; \
        bfr[j] = *(const bf16x8*)((const char*)Bsm[bi] + rn * 128 + ((u ^ (rn & 7)) << 4)); \
      } \
      _Pragma("unroll") \
      for (int i = 0; i < 8; ++i) { \
        const int m = wm * 128 + i * 16 + c_; \
        const bf16x8 af = *(const bf16x8*)((const char*)Asm[bi] + m * 128 + ((u ^ (m & 7)) << 4)); \
        acc[i][0] = __builtin_amdgcn_mfma_f32_16x16x32_bf16(af, bfr[0], acc[i][0], 0, 0, 0); \
        acc[i][1] = __builtin_amdgcn_mfma_f32_16x16x32_bf16(af, bfr[1], acc[i][1], 0, 0, 0); \
      } \
    } \
  } while (0)

  // ---- prologue (R13 verbatim)
  ISSUE_A(0, s0);
  ISSUE_B(s0);
  asm volatile("s_waitcnt vmcnt(0)" ::: "memory");
  WRITE_B(0);
  BARRIER();
  if (s0 + 1 < s1) { ISSUE_A(1, s0 + 1); ISSUE_B(s0 + 1); }

  for (int s = s0; s < s1; ++s) {
    const int cur = (s - s0) & 1;
    COMPUTE(cur);
    if (s + 1 < s1) {
      asm volatile("s_waitcnt vmcnt(0)" ::: "memory");  // A(s+1) DMA + B(s+1) regs
      WRITE_B(cur ^ 1);
    }
    BARRIER();
    if (s + 2 < s1) { ISSUE_A(cur, s + 2); ISSUE_B(s + 2); }
  }

  // ---- epilogue: bf16 partial slice [ks][n][m] (m fastest, 4 per lane)
  __bf16* out = h_part + (size_t)ks * DHID * B_SZ;
  #pragma unroll
  for (int j = 0; j < 2; ++j) {
    const int n = n0 + wn * 32 + j * 16 + c_;
    #pragma unroll
    for (int i = 0; i < 8; ++i) {
      const int mb = wm * 128 + i * 16 + q_ * 4;
      bf16x4 pv;
      pv[0] = (__bf16)acc[i][j][0]; pv[1] = (__bf16)acc[i][j][1];
      pv[2] = (__bf16)acc[i][j][2]; pv[3] = (__bf16)acc[i][j][3];
      *(bf16x4*)(out + (size_t)n * B_SZ + mb) = pv;
    }
  }
#undef ISSUE_A
#undef ISSUE_B
#undef WRITE_B
#undef COMPUTE
}

// ---------------------------------------------------------------------------
// Kernel C: reduce bf16 split-K partials, add b1, relu -> h[m][n] (fp32)
// ---------------------------------------------------------------------------
__global__ __launch_bounds__(256) void reduce_kernel(const __bf16* __restrict__ h_part,
                                                     const float* __restrict__ b1,
                                                     float* __restrict__ h) {
  const int n = blockIdx.x;
  const int m = threadIdx.x;
  float s = 0.f;
  #pragma unroll 6
  for (int ks = 0; ks < KSPLIT; ++ks)
    s += (float)h_part[((size_t)ks * DHID + n) * B_SZ + m];
  float v = s + b1[n];
  h[(size_t)m * DHID + n] = v > 0.f ? v : 0.f;
}

// ---------------------------------------------------------------------------
// Kernel D: logits = h @ W2^T + b2. One wave per batch row.
// ---------------------------------------------------------------------------
__global__ __launch_bounds__(64) void head_kernel(const float* __restrict__ h,
                                                  const float* __restrict__ W2,
                                                  const float* __restrict__ b2,
                                                  float* __restrict__ logits) {
  const int m = blockIdx.x;
  const int lane = threadIdx.x;
  float hv[12];
  #pragma unroll
  for (int j = 0; j < 12; ++j) hv[j] = h[(size_t)m * DHID + j * 64 + lane];
  #pragma unroll
  for (int c = 0; c < NCLS; ++c) {
    float s = 0.f;
    #pragma unroll
    for (int j = 0; j < 12; ++j) s += hv[j] * W2[c * DHID + j * 64 + lane];
    #pragma unroll
    for (int off = 32; off > 0; off >>= 1) s += __shfl_xor(s, off);
    if (lane == 0) logits[m * NCLS + c] = s + b2[c];
  }
}

// ---------------------------------------------------------------------------
extern "C" void kernel_launch(void* const* d_in, const int* in_sizes, int n_in,
                              void* d_out, int out_size, void* d_ws, size_t ws_size,
                              hipStream_t stream) {
  const float* feat = (const float*)d_in[0];
  const float* W1   = (const float*)d_in[1];
  const float* b1   = (const float*)d_in[2];
  const float* W2   = (const float*)d_in[3];
  const float* b2   = (const float*)d_in[4];

  float* logits   = (float*)d_out;
  float* feat_out = (float*)d_out + (size_t)B_SZ * NCLS;

  char* ws = (char*)d_ws;
  __bf16* pcam   = (__bf16*)ws;                                   // 25.7 MB
  __bf16* h_part = (__bf16*)(ws + (size_t)B_SZ * KDIM * 2);       // 16.5 MB
  float*  h      = (float*)(ws + (size_t)B_SZ * KDIM * 2
                               + (size_t)KSPLIT * DHID * B_SZ * 2); // 786 KB

  pcam_kernel<<<(B_SZ * C_SZ) / 32, 256, 0, stream>>>(feat, feat_out, pcam);
  gemm1_kernel<<<dim3(NT, KSPLIT), 512, 0, stream>>>(pcam, W1, h_part);
  reduce_kernel<<<DHID, 256, 0, stream>>>(h_part, b1, h);
  head_kernel<<<B_SZ, 64, 0, stream>>>(h, W2, b2, logits);
}